// Round 13
// baseline (1127.098 us; speedup 1.0000x reference)
//
#include <hip/hip_runtime.h>

#define NN 4096
#define NC 10
#define NW 64            // u64 words per adjacency row (permuted layout)
#define CHW 16           // words per chunk
#define NCHUNK 4
#define BH 32            // tile = 32x32 pairs, 64 rows staged
typedef unsigned long long u64;
typedef long long s64;

#define S1F 0.73105857863000489f   // sigmoid(1.0)

// permuted bit layout: col c -> word W(c)=4*(c>>8)+(c&3), bit (c>>2)&63
#define COLW(c) (4 * ((c) >> 8) + ((c) & 3))
#define COLB(c) (((c) >> 2) & 63)

// ws layout (bytes)
#define OFF_BITS   0           // 4096*64*8 = 2097152
#define OFF_DEG    2097152     // int[4096]
#define OFF_POS    2113536     // float[4096]
#define OFF_LIST   2129920     // int[4096]
#define OFF_ACC    2146304     // 1536 B strip
#define OFF_CNT    2147840     // int[10][4096] = 163840 (memset with acc)
// acc strip offsets
#define A_CE    0
#define A_LOSS  4
#define A_MCNT  8
#define A_NCNT  16    // 10 ints
#define A_GD    64    // 10 ints
#define A_GE    128   // 100 ints
#define A_GSI   528   // 100 u64

// ---- kernel 1: pack bits (int4 loads, permuted layout) + deg + cnt --------
__global__ __launch_bounds__(256) void pack_bits_kernel(
    const int* __restrict__ adj, u64* __restrict__ bits, int* __restrict__ deg,
    int* __restrict__ cnt, const int* __restrict__ labels,
    const int* __restrict__ mask) {
  int p = blockIdx.x;
  if (mask[p] == 0) return;
  int tid = threadIdx.x;
  int wv = tid >> 6, lane = tid & 63;
  const int4* row = (const int4*)(adj + (size_t)p * NN);
  int lb = labels[p];
  int dcnt = 0;
#pragma unroll
  for (int g = 0; g < 4; g++) {
    int4 v = row[g * 256 + tid];
    u64 b0 = __ballot(v.x != 0);
    u64 b1 = __ballot(v.y != 0);
    u64 b2 = __ballot(v.z != 0);
    u64 b3 = __ballot(v.w != 0);
    if (lane == 0) {             // word W=16g+4wv+k holds cols {1024g+256wv+4l+k}
      int W = 16 * g + 4 * wv;
      u64* dst = bits + (size_t)p * NW + W;
      dst[0] = b0; dst[1] = b1; dst[2] = b2; dst[3] = b3;
    }
    int base = (g * 256 + tid) << 2;
    if (v.x) { dcnt++; atomicAdd(&cnt[lb * NN + base], 1); }
    if (v.y) { dcnt++; atomicAdd(&cnt[lb * NN + base + 1], 1); }
    if (v.z) { dcnt++; atomicAdd(&cnt[lb * NN + base + 2], 1); }
    if (v.w) { dcnt++; atomicAdd(&cnt[lb * NN + base + 3], 1); }
  }
  __shared__ int red[256];
  red[tid] = dcnt;
  __syncthreads();
  for (int s = 128; s > 0; s >>= 1) {
    if (tid < s) red[tid] += red[tid + s];
    __syncthreads();
  }
  if (tid == 0) deg[p] = red[0];
}

// ---- kernel 2 (merged): node CE/pos/Ncnt (blk 0-15), compaction (blk 16),
//      class-pair aggregates (blk 17-32) -----------------------------------
__global__ __launch_bounds__(256) void mid_kernel(
    const float* __restrict__ preds, const int* __restrict__ labels,
    const int* __restrict__ mask, const u64* __restrict__ bits,
    const int* __restrict__ deg, const int* __restrict__ cnt,
    float* __restrict__ pos, int* __restrict__ Ncnt, float* __restrict__ ceAcc,
    int* __restrict__ list, int* __restrict__ Mcount,
    u64* __restrict__ gSI, int* __restrict__ gE, int* __restrict__ gD) {
  int tid = threadIdx.x;
  int blk = blockIdx.x;
  if (blk < 16) {                              // per-node CE + pos + Ncnt
    int n = blk * 256 + tid;
    int l = labels[n];
    float r[NC];
    float mx = -1e30f, rl = 0.f;
#pragma unroll
    for (int c = 0; c < NC; c++) {
      float v = preds[n * NC + c];
      r[c] = v;
      if (c == l) rl = v;
      mx = fmaxf(mx, v);
    }
    float s = 0.f;
#pragma unroll
    for (int c = 0; c < NC; c++) s += expf(r[c] - mx);
    pos[n] = rl;
    float ce = mx + logf(s) - rl;
    if (mask[n] != 0) atomicAdd(&Ncnt[l], 1);
    __shared__ float red[256];
    red[tid] = ce;
    __syncthreads();
    for (int st = 128; st > 0; st >>= 1) {
      if (tid < st) red[tid] += red[tid + st];
      __syncthreads();
    }
    if (tid == 0) atomicAdd(ceAcc, red[0]);
  } else if (blk == 16) {                      // deterministic compaction
    __shared__ int cnt2[256];
    int base = tid * 16;
    int c = 0;
    for (int i = 0; i < 16; i++) c += (mask[base + i] != 0) ? 1 : 0;
    cnt2[tid] = c;
    __syncthreads();
    for (int s = 1; s < 256; s <<= 1) {
      int v = (tid >= s) ? cnt2[tid - s] : 0;
      __syncthreads();
      cnt2[tid] += v;
      __syncthreads();
    }
    int off = cnt2[tid] - c;
    for (int i = 0; i < 16; i++) {
      int idx = base + i;
      if (mask[idx] != 0) list[off++] = idx;
    }
    if (tid == 255) *Mcount = cnt2[255];
  } else {                                     // class aggregates
    __shared__ int eb[100], db[10];
    for (int b = tid; b < 100; b += 256) eb[b] = 0;
    if (tid < 10) db[tid] = 0;
    __syncthreads();
    int r = (blk - 17) * 256 + tid;
    int c[10];
#pragma unroll
    for (int i = 0; i < NC; i++) c[i] = cnt[i * NN + r];
    int sI[55];
    {
      int k = 0;
#pragma unroll
      for (int i = 0; i < NC; i++)
#pragma unroll
        for (int j = i; j < NC; j++) { sI[k] = c[i] * c[j]; k++; }
    }
#pragma unroll
    for (int k = 0; k < 55; k++) {
      int v = sI[k];
      for (int d = 1; d < 64; d <<= 1) v += __shfl_xor(v, d);
      sI[k] = v;
    }
    if ((tid & 63) == 0) {
      int k = 0;
      for (int i = 0; i < NC; i++)
        for (int j = i; j < NC; j++) {
          u64 v = (u64)(unsigned int)sI[k];
          if (v) {
            atomicAdd(&gSI[i * NC + j], v);
            if (i != j) atomicAdd(&gSI[j * NC + i], v);
          }
          k++;
        }
    }
    if (mask[r] != 0) {
      int lr = labels[r];
      atomicAdd(&db[lr], deg[r]);
      int selfr = (int)((bits[(size_t)r * NW + COLW(r)] >> COLB(r)) & 1ULL);
      if (!selfr) {
#pragma unroll
        for (int i = 0; i < NC; i++)
          if (c[i]) atomicAdd(&eb[i * NC + lr], c[i]);
      }
    }
    __syncthreads();
    for (int b = tid; b < 100; b += 256) if (eb[b]) atomicAdd(&gE[b], eb[b]);
    if (tid < 10 && db[tid]) atomicAdd(&gD[tid], db[tid]);
  }
}

// ---- kernel 3: R8 pair kernel + chunk double-buffer (only change) ---------
// 32x32 tile/wave, 4-wave blocks, word-major swizzled TBW, predT staged,
// epilogue scatter loaded under chunk-3 popc. New: pfA/pfB single-ahead
// double-buffer so each chunk's global-load latency hides under the previous
// chunk's popcount (R8 exposed it 4x/tile). All indexing static; peak VGPR
// ~= R8's (pfB dead when rwp/ef load at chunk 3).
__global__ __launch_bounds__(256, 2) void pair_kernel(
    const u64* __restrict__ bits, const int* __restrict__ deg,
    const float* __restrict__ pos, const float* __restrict__ preds,
    const int* __restrict__ labels, const int* __restrict__ list,
    const int* __restrict__ Mcount, const int* __restrict__ Ncnt,
    const u64* __restrict__ gSI, const int* __restrict__ gE,
    const int* __restrict__ gD, float* __restrict__ gLoss) {
  __shared__ __align__(16) u64 TBW[4][CHW][64];   // 32 KB word-major swizzled
  __shared__ float predT[4][64][NC];              // 10 KB
  __shared__ int mNode[4][64], mLab[4][64], mDeg[4][64], mSelf[4][64];
  __shared__ float mPos[4][64];
  __shared__ float wLDS[100];
  __shared__ float wred[4];

  int tid = threadIdx.x;
  int wv = tid >> 6, lane = tid & 63;

  // class-pair weights from exact integer aggregates (gate + PER/(Ni*Nj))
  if (tid < 100) {
    int i = tid / NC, j = tid - (tid / NC) * NC;
    s64 SI = (s64)gSI[tid];
    s64 ssub = (s64)gD[i] * (s64)Ncnt[j] - SI - (s64)gE[tid];
    float w = 0.f;
    if (i != j && ssub > 0 && SI > 0) {
      float Ni = fmaxf((float)Ncnt[i], 1.f);
      float Nj = fmaxf((float)Ncnt[j], 1.f);
      w = 0.001f / (Ni * Nj);
    }
    wLDS[tid] = w;
  }
  __syncthreads();

  int M = *Mcount;
  int ntp = (M + BH - 1) / BH;
  int ntiles = (ntp * (ntp + 1)) >> 1;
  int gw = blockIdx.x * 4 + wv;
  int nw = gridDim.x * 4;

  int lp = lane >> 3, lq = lane & 7;          // 8x8 lane grid, 4x4 pairs each
  // swizzled 16B-unit slots: sigma(u) = u ^ ((u>>3)&1)  (validated R8)
  int uP0 = 2 * lp, uP1 = 2 * lp + 1;
  int uQ0 = 16 + 2 * lq, uQ1 = 17 + 2 * lq;
  int rdP0 = (uP0 ^ ((uP0 >> 3) & 1)) << 1;
  int rdP1 = (uP1 ^ ((uP1 >> 3) & 1)) << 1;
  int rdQ0 = (uQ0 ^ ((uQ0 >> 3) & 1)) << 1;
  int rdQ1 = (uQ1 ^ ((uQ1 >> 3) & 1)) << 1;
  int uw = lane >> 1;
  int wslot = ((uw ^ ((uw >> 3) & 1)) << 1) + (lane & 1);

  float lsum = 0.f;
  ulonglong2 z2 = make_ulonglong2(0ULL, 0ULL);

  for (int t = gw; t < ntiles; t += nw) {
    int tp = 0, rem = t;
    while (rem >= ntp - tp) { rem -= ntp - tp; tp++; }
    int tq = tp + rem;
    bool diag = (tp == tq);

    // per-row metadata + preds staging (lane owns row `lane`: 0-31 P, 32-63 Q)
    int mi = (lane < BH) ? (tp * BH + lane) : (tq * BH + (lane - BH));
    int nd = (mi < M) ? list[mi] : -1;
    mNode[wv][lane] = nd;
    mLab[wv][lane]  = (nd >= 0) ? labels[nd] : -1;
    mDeg[wv][lane]  = (nd >= 0) ? deg[nd] : 0;
    mPos[wv][lane]  = (nd >= 0) ? pos[nd] : 0.f;
    mSelf[wv][lane] = (nd >= 0) ? (int)((bits[(size_t)nd * NW + COLW(nd)] >> COLB(nd)) & 1ULL) : 0;
#pragma unroll
    for (int cc = 0; cc < NC; cc++)
      predT[wv][lane][cc] = (nd >= 0) ? preds[nd * NC + cc] : 0.f;

    const ulonglong2* rp2 = (const ulonglong2*)(bits + (size_t)((nd >= 0) ? nd : 0) * NW);
    bool live = (nd >= 0);

    int acc[4][4];
#pragma unroll
    for (int i = 0; i < 4; i++)
#pragma unroll
      for (int j = 0; j < 4; j++) acc[i][j] = 0;

    u64 rwp[4][4], rwq[4][4];   // per-pair adjacency words (loaded at c==3)

    // chunk 0 loads
    ulonglong2 pfA[8], pfB[8];
#pragma unroll
    for (int x = 0; x < 8; x++) pfA[x] = live ? rp2[x] : z2;

#define POPC_CHUNK()                                                    \
    do {                                                                \
      asm volatile("s_waitcnt lgkmcnt(0)" ::: "memory");                \
      __builtin_amdgcn_sched_barrier(0);                                \
      _Pragma("unroll")                                                 \
      for (int y = 0; y < CHW; y++) {                                   \
        ulonglong2 P0 = *(ulonglong2*)&TBW[wv][y][rdP0];                \
        ulonglong2 P1 = *(ulonglong2*)&TBW[wv][y][rdP1];                \
        ulonglong2 Q0 = *(ulonglong2*)&TBW[wv][y][rdQ0];                \
        ulonglong2 Q1 = *(ulonglong2*)&TBW[wv][y][rdQ1];                \
        u64 p[4] = {P0.x, P0.y, P1.x, P1.y};                            \
        u64 q[4] = {Q0.x, Q0.y, Q1.x, Q1.y};                            \
        _Pragma("unroll")                                               \
        for (int i = 0; i < 4; i++)                                     \
          _Pragma("unroll")                                             \
          for (int j = 0; j < 4; j++)                                   \
            acc[i][j] += (int)__popcll(p[i] & q[j]);                    \
      }                                                                 \
    } while (0)

#define WRITE_LDS(BUF)                                                  \
    do {                                                                \
      _Pragma("unroll")                                                 \
      for (int x = 0; x < 8; x++) {                                     \
        TBW[wv][2 * x][wslot]     = BUF[x].x;                           \
        TBW[wv][2 * x + 1][wslot] = BUF[x].y;                           \
      }                                                                 \
    } while (0)

    // step 0: write chunk0, load chunk1, popc chunk0
    WRITE_LDS(pfA);
#pragma unroll
    for (int x = 0; x < 8; x++) pfB[x] = live ? rp2[8 + x] : z2;
    POPC_CHUNK();
    // step 1: write chunk1, load chunk2, popc chunk1
    WRITE_LDS(pfB);
#pragma unroll
    for (int x = 0; x < 8; x++) pfA[x] = live ? rp2[16 + x] : z2;
    POPC_CHUNK();
    // step 2: write chunk2, load chunk3, popc chunk2
    WRITE_LDS(pfA);
#pragma unroll
    for (int x = 0; x < 8; x++) pfB[x] = live ? rp2[24 + x] : z2;
    POPC_CHUNK();
    // step 3: write chunk3, load epilogue scatter, popc chunk3
    WRITE_LDS(pfB);
    {
#pragma unroll
      for (int i = 0; i < 4; i++) {
        int pg = mNode[wv][4 * lp + i]; pg = (pg >= 0) ? pg : 0;
#pragma unroll
        for (int j = 0; j < 4; j++) {
          int qg = mNode[wv][BH + 4 * lq + j]; qg = (qg >= 0) ? qg : 0;
          rwp[i][j] = bits[(size_t)pg * NW + COLW(qg)];
          rwq[i][j] = bits[(size_t)qg * NW + COLW(pg)];
        }
      }
    }
    POPC_CHUNK();
#undef POPC_CHUNK
#undef WRITE_LDS

    // epilogue: registers + per-wave meta/pred LDS
#pragma unroll
    for (int i = 0; i < 4; i++) {
      int pl = 4 * lp + i;
      int pg = mNode[wv][pl];
      if (pg < 0) continue;
      int li  = mLab[wv][pl];
      int dgp = mDeg[wv][pl];
      int sp  = mSelf[wv][pl];
      float pp = mPos[wv][pl];
#pragma unroll
      for (int j = 0; j < 4; j++) {
        int qr = 4 * lq + j;
        int qg = mNode[wv][BH + qr];
        if (qg < 0) continue;
        int lj = mLab[wv][BH + qr];
        if (li == lj) continue;               // off-diag class bins only
        if (diag && pl >= qr) continue;       // unordered once on diag tiles
        int inter = acc[i][j];
        int apq = (int)((rwp[i][j] >> COLB(qg)) & 1ULL);
        int aqp = (int)((rwq[i][j] >> COLB(pg)) & 1ULL);
        int sq  = mSelf[wv][BH + qr];
        int sub_f = dgp - inter - (apq & (sq ^ 1));
        int sub_r = mDeg[wv][BH + qr] - inter - (aqp & (sp ^ 1));
        float rden = 1.f / (1.f + S1F * (float)inter);
        float xf = (1.f + S1F * (float)sub_f) * rden;
        float xr = (1.f + S1F * (float)sub_r) * rden;
        float Ef = __expf(predT[wv][BH + qr][li] - pp);
        float Er = __expf(predT[wv][pl][lj] - mPos[wv][BH + qr]);
        float vf = 1.f / (1.f + __expf(xf));  // 1 - sigmoid(x)
        float vr = 1.f / (1.f + __expf(xr));
        lsum += Ef * vf * wLDS[li * NC + lj] + Er * vr * wLDS[lj * NC + li];
      }
    }
    // next tile: wave-order DS makes LDS rewrite safe without barriers
  }

  // block reduce: wave shuffle -> 4 partials -> one atomic
  for (int d = 1; d < 64; d <<= 1) lsum += __shfl_xor(lsum, d);
  if (lane == 0) wred[wv] = lsum;
  __syncthreads();
  if (tid == 0) atomicAdd(gLoss, wred[0] + wred[1] + wred[2] + wred[3]);
}

// ---- kernel 4: final assembly ---------------------------------------------
__global__ void fin_kernel(const float* __restrict__ ceAcc,
                           const float* __restrict__ gLoss,
                           float* __restrict__ out) {
  out[0] = ceAcc[0] / (float)NN + gLoss[0];
}

// ---- launch ---------------------------------------------------------------
extern "C" void kernel_launch(void* const* d_in, const int* in_sizes, int n_in,
                              void* d_out, int out_size, void* d_ws, size_t ws_size,
                              hipStream_t stream) {
  const float* preds  = (const float*)d_in[0];
  const int*   labels = (const int*)d_in[1];
  const int*   mask   = (const int*)d_in[2];
  const int*   adj    = (const int*)d_in[3];

  char* ws = (char*)d_ws;
  u64*   bits  = (u64*)(ws + OFF_BITS);
  int*   deg   = (int*)(ws + OFF_DEG);
  float* pos   = (float*)(ws + OFF_POS);
  int*   list  = (int*)(ws + OFF_LIST);
  char*  accb  = ws + OFF_ACC;
  float* ceAcc = (float*)(accb + A_CE);
  float* gLoss = (float*)(accb + A_LOSS);
  int*   Mcnt  = (int*)(accb + A_MCNT);
  int*   Ncnt  = (int*)(accb + A_NCNT);
  int*   gD    = (int*)(accb + A_GD);
  int*   gE    = (int*)(accb + A_GE);
  u64*   gSI   = (u64*)(accb + A_GSI);
  int*   cnt   = (int*)(ws + OFF_CNT);

  hipMemsetAsync(ws + OFF_ACC, 0, 1536 + 163840, stream);

  hipLaunchKernelGGL(pack_bits_kernel, dim3(NN), dim3(256), 0, stream,
                     adj, bits, deg, cnt, labels, mask);
  hipLaunchKernelGGL(mid_kernel, dim3(33), dim3(256), 0, stream,
                     preds, labels, mask, bits, deg, cnt,
                     pos, Ncnt, ceAcc, list, Mcnt, gSI, gE, gD);
  // M=2048 -> 2080 tiles; 520 blocks x 4 waves = 2080 (1 tile/wave)
  hipLaunchKernelGGL(pair_kernel, dim3(520), dim3(256), 0, stream,
                     bits, deg, pos, preds, labels, list, Mcnt, Ncnt,
                     gSI, gE, gD, gLoss);
  hipLaunchKernelGGL(fin_kernel, dim3(1), dim3(1), 0, stream,
                     ceAcc, gLoss, (float*)d_out);
}

// Round 14
// 85.463 us; speedup vs baseline: 13.1881x; 13.1881x over previous
//
#include <hip/hip_runtime.h>

#define NN 4096
#define NC 10
#define NW 64            // u64 words per adjacency row (permuted layout)
#define CHW 16           // words per chunk
#define NCHUNK 4
#define BH 32            // tile = 32x32 pairs, 64 rows staged
typedef unsigned long long u64;
typedef long long s64;

#define S1F 0.73105857863000489f   // sigmoid(1.0)

// permuted bit layout: col c -> word W(c)=4*(c>>8)+(c&3), bit (c>>2)&63
#define COLW(c) (4 * ((c) >> 8) + ((c) & 3))
#define COLB(c) (((c) >> 2) & 63)

// ws layout (bytes)
#define OFF_BITS   0           // 4096*64*8 = 2097152
#define OFF_DEG    2097152     // int[4096]
#define OFF_POS    2113536     // float[4096]
#define OFF_LIST   2129920     // int[4096]
#define OFF_ACC    2146304     // 1536 B strip
#define OFF_CNT    2147840     // int[10][4096] = 163840 (memset with acc)
// acc strip offsets
#define A_CE    0
#define A_LOSS  4
#define A_MCNT  8
#define A_NCNT  16    // 10 ints
#define A_GD    64    // 10 ints
#define A_GE    128   // 100 ints
#define A_GSI   528   // 100 u64

// ---- kernel 1: pack bits (int4 loads, permuted layout) + deg + cnt --------
__global__ __launch_bounds__(256) void pack_bits_kernel(
    const int* __restrict__ adj, u64* __restrict__ bits, int* __restrict__ deg,
    int* __restrict__ cnt, const int* __restrict__ labels,
    const int* __restrict__ mask) {
  int p = blockIdx.x;
  if (mask[p] == 0) return;
  int tid = threadIdx.x;
  int wv = tid >> 6, lane = tid & 63;
  const int4* row = (const int4*)(adj + (size_t)p * NN);
  int lb = labels[p];
  int dcnt = 0;
#pragma unroll
  for (int g = 0; g < 4; g++) {
    int4 v = row[g * 256 + tid];
    u64 b0 = __ballot(v.x != 0);
    u64 b1 = __ballot(v.y != 0);
    u64 b2 = __ballot(v.z != 0);
    u64 b3 = __ballot(v.w != 0);
    if (lane == 0) {             // word W=16g+4wv+k holds cols {1024g+256wv+4l+k}
      int W = 16 * g + 4 * wv;
      u64* dst = bits + (size_t)p * NW + W;
      dst[0] = b0; dst[1] = b1; dst[2] = b2; dst[3] = b3;
    }
    int base = (g * 256 + tid) << 2;
    if (v.x) { dcnt++; atomicAdd(&cnt[lb * NN + base], 1); }
    if (v.y) { dcnt++; atomicAdd(&cnt[lb * NN + base + 1], 1); }
    if (v.z) { dcnt++; atomicAdd(&cnt[lb * NN + base + 2], 1); }
    if (v.w) { dcnt++; atomicAdd(&cnt[lb * NN + base + 3], 1); }
  }
  __shared__ int red[256];
  red[tid] = dcnt;
  __syncthreads();
  for (int s = 128; s > 0; s >>= 1) {
    if (tid < s) red[tid] += red[tid + s];
    __syncthreads();
  }
  if (tid == 0) deg[p] = red[0];
}

// ---- kernel 2 (merged): node CE/pos/Ncnt (blk 0-15), compaction (blk 16),
//      class-pair aggregates (blk 17-32) -----------------------------------
__global__ __launch_bounds__(256) void mid_kernel(
    const float* __restrict__ preds, const int* __restrict__ labels,
    const int* __restrict__ mask, const u64* __restrict__ bits,
    const int* __restrict__ deg, const int* __restrict__ cnt,
    float* __restrict__ pos, int* __restrict__ Ncnt, float* __restrict__ ceAcc,
    int* __restrict__ list, int* __restrict__ Mcount,
    u64* __restrict__ gSI, int* __restrict__ gE, int* __restrict__ gD) {
  int tid = threadIdx.x;
  int blk = blockIdx.x;
  if (blk < 16) {                              // per-node CE + pos + Ncnt
    int n = blk * 256 + tid;
    int l = labels[n];
    float r[NC];
    float mx = -1e30f, rl = 0.f;
#pragma unroll
    for (int c = 0; c < NC; c++) {
      float v = preds[n * NC + c];
      r[c] = v;
      if (c == l) rl = v;
      mx = fmaxf(mx, v);
    }
    float s = 0.f;
#pragma unroll
    for (int c = 0; c < NC; c++) s += expf(r[c] - mx);
    pos[n] = rl;
    float ce = mx + logf(s) - rl;
    if (mask[n] != 0) atomicAdd(&Ncnt[l], 1);
    __shared__ float red[256];
    red[tid] = ce;
    __syncthreads();
    for (int st = 128; st > 0; st >>= 1) {
      if (tid < st) red[tid] += red[tid + st];
      __syncthreads();
    }
    if (tid == 0) atomicAdd(ceAcc, red[0]);
  } else if (blk == 16) {                      // deterministic compaction
    __shared__ int cnt2[256];
    int base = tid * 16;
    int c = 0;
    for (int i = 0; i < 16; i++) c += (mask[base + i] != 0) ? 1 : 0;
    cnt2[tid] = c;
    __syncthreads();
    for (int s = 1; s < 256; s <<= 1) {
      int v = (tid >= s) ? cnt2[tid - s] : 0;
      __syncthreads();
      cnt2[tid] += v;
      __syncthreads();
    }
    int off = cnt2[tid] - c;
    for (int i = 0; i < 16; i++) {
      int idx = base + i;
      if (mask[idx] != 0) list[off++] = idx;
    }
    if (tid == 255) *Mcount = cnt2[255];
  } else {                                     // class aggregates
    __shared__ int eb[100], db[10];
    for (int b = tid; b < 100; b += 256) eb[b] = 0;
    if (tid < 10) db[tid] = 0;
    __syncthreads();
    int r = (blk - 17) * 256 + tid;
    int c[10];
#pragma unroll
    for (int i = 0; i < NC; i++) c[i] = cnt[i * NN + r];
    int sI[55];
    {
      int k = 0;
#pragma unroll
      for (int i = 0; i < NC; i++)
#pragma unroll
        for (int j = i; j < NC; j++) { sI[k] = c[i] * c[j]; k++; }
    }
#pragma unroll
    for (int k = 0; k < 55; k++) {
      int v = sI[k];
      for (int d = 1; d < 64; d <<= 1) v += __shfl_xor(v, d);
      sI[k] = v;
    }
    if ((tid & 63) == 0) {
      int k = 0;
      for (int i = 0; i < NC; i++)
        for (int j = i; j < NC; j++) {
          u64 v = (u64)(unsigned int)sI[k];
          if (v) {
            atomicAdd(&gSI[i * NC + j], v);
            if (i != j) atomicAdd(&gSI[j * NC + i], v);
          }
          k++;
        }
    }
    if (mask[r] != 0) {
      int lr = labels[r];
      atomicAdd(&db[lr], deg[r]);
      int selfr = (int)((bits[(size_t)r * NW + COLW(r)] >> COLB(r)) & 1ULL);
      if (!selfr) {
#pragma unroll
        for (int i = 0; i < NC; i++)
          if (c[i]) atomicAdd(&eb[i * NC + lr], c[i]);
      }
    }
    __syncthreads();
    for (int b = tid; b < 100; b += 256) if (eb[b]) atomicAdd(&gE[b], eb[b]);
    if (tid < 10 && db[tid]) atomicAdd(&gD[tid], db[tid]);
  }
}

// ---- kernel 3: R8 pair kernel, verbatim structure (proven 46 us, VGPR 80) -
// 32x32 tile/wave, 4-wave blocks, single pf buffer per chunk, word-major
// swizzled TBW, predT staged in LDS, rwp/rwq prefetched at chunk 3 only.
// Only change vs R8: COLW/COLB for the permuted bit layout.
__global__ __launch_bounds__(256, 2) void pair_kernel(
    const u64* __restrict__ bits, const int* __restrict__ deg,
    const float* __restrict__ pos, const float* __restrict__ preds,
    const int* __restrict__ labels, const int* __restrict__ list,
    const int* __restrict__ Mcount, const int* __restrict__ Ncnt,
    const u64* __restrict__ gSI, const int* __restrict__ gE,
    const int* __restrict__ gD, float* __restrict__ gLoss) {
  __shared__ __align__(16) u64 TBW[4][CHW][64];   // 32 KB word-major swizzled
  __shared__ float predT[4][64][NC];              // 10 KB
  __shared__ int mNode[4][64], mLab[4][64], mDeg[4][64], mSelf[4][64];
  __shared__ float mPos[4][64];
  __shared__ float wLDS[100];
  __shared__ float wred[4];

  int tid = threadIdx.x;
  int wv = tid >> 6, lane = tid & 63;

  // class-pair weights from exact integer aggregates (gate + PER/(Ni*Nj))
  if (tid < 100) {
    int i = tid / NC, j = tid - (tid / NC) * NC;
    s64 SI = (s64)gSI[tid];
    s64 ssub = (s64)gD[i] * (s64)Ncnt[j] - SI - (s64)gE[tid];
    float w = 0.f;
    if (i != j && ssub > 0 && SI > 0) {
      float Ni = fmaxf((float)Ncnt[i], 1.f);
      float Nj = fmaxf((float)Ncnt[j], 1.f);
      w = 0.001f / (Ni * Nj);
    }
    wLDS[tid] = w;
  }
  __syncthreads();

  int M = *Mcount;
  int ntp = (M + BH - 1) / BH;
  int ntiles = (ntp * (ntp + 1)) >> 1;
  int gw = blockIdx.x * 4 + wv;
  int nw = gridDim.x * 4;

  int lp = lane >> 3, lq = lane & 7;          // 8x8 lane grid, 4x4 pairs each
  // swizzled 16B-unit slots: sigma(u) = u ^ ((u>>3)&1)
  int uP0 = 2 * lp, uP1 = 2 * lp + 1;
  int uQ0 = 16 + 2 * lq, uQ1 = 17 + 2 * lq;
  int rdP0 = (uP0 ^ ((uP0 >> 3) & 1)) << 1;
  int rdP1 = (uP1 ^ ((uP1 >> 3) & 1)) << 1;
  int rdQ0 = (uQ0 ^ ((uQ0 >> 3) & 1)) << 1;
  int rdQ1 = (uQ1 ^ ((uQ1 >> 3) & 1)) << 1;
  int uw = lane >> 1;
  int wslot = ((uw ^ ((uw >> 3) & 1)) << 1) + (lane & 1);

  float lsum = 0.f;

  for (int t = gw; t < ntiles; t += nw) {
    int tp = 0, rem = t;
    while (rem >= ntp - tp) { rem -= ntp - tp; tp++; }
    int tq = tp + rem;
    bool diag = (tp == tq);

    // per-row metadata + preds staging (lane owns row `lane`: 0-31 P, 32-63 Q)
    int mi = (lane < BH) ? (tp * BH + lane) : (tq * BH + (lane - BH));
    int nd = (mi < M) ? list[mi] : -1;
    mNode[wv][lane] = nd;
    mLab[wv][lane]  = (nd >= 0) ? labels[nd] : -1;
    mDeg[wv][lane]  = (nd >= 0) ? deg[nd] : 0;
    mPos[wv][lane]  = (nd >= 0) ? pos[nd] : 0.f;
    mSelf[wv][lane] = (nd >= 0) ? (int)((bits[(size_t)nd * NW + COLW(nd)] >> COLB(nd)) & 1ULL) : 0;
#pragma unroll
    for (int cc = 0; cc < NC; cc++)
      predT[wv][lane][cc] = (nd >= 0) ? preds[nd * NC + cc] : 0.f;

    const u64* rowp = bits + (size_t)((nd >= 0) ? nd : 0) * NW;
    bool live = (nd >= 0);

    int acc[4][4];
#pragma unroll
    for (int i = 0; i < 4; i++)
#pragma unroll
      for (int j = 0; j < 4; j++) acc[i][j] = 0;

    u64 rwp[4][4], rwq[4][4];   // per-pair adjacency words (loaded at c==3)

    for (int c = 0; c < NCHUNK; c++) {
      // stage chunk c: 16 words of my row into word-major swizzled slots
      ulonglong2 pf[8];
      const u64* src = rowp + c * CHW;
#pragma unroll
      for (int x = 0; x < 8; x++)
        pf[x] = live ? *(const ulonglong2*)(src + (x << 1))
                     : make_ulonglong2(0ULL, 0ULL);
#pragma unroll
      for (int x = 0; x < 8; x++) {
        TBW[wv][2 * x][wslot]     = pf[x].x;
        TBW[wv][2 * x + 1][wslot] = pf[x].y;
      }
      if (c == NCHUNK - 1) {
        // issue epilogue scattered loads; latency hides under last popc chunk
#pragma unroll
        for (int i = 0; i < 4; i++) {
          int pg = mNode[wv][4 * lp + i]; pg = (pg >= 0) ? pg : 0;
#pragma unroll
          for (int j = 0; j < 4; j++) {
            int qg = mNode[wv][BH + 4 * lq + j]; qg = (qg >= 0) ? qg : 0;
            rwp[i][j] = bits[(size_t)pg * NW + COLW(qg)];
            rwq[i][j] = bits[(size_t)qg * NW + COLW(pg)];
          }
        }
      }
      // wave-synchronous: drain DS writes before reads (no block barrier)
      asm volatile("s_waitcnt lgkmcnt(0)" ::: "memory");
      __builtin_amdgcn_sched_barrier(0);

#pragma unroll 4
      for (int y = 0; y < CHW; y++) {
        ulonglong2 P0 = *(ulonglong2*)&TBW[wv][y][rdP0];
        ulonglong2 P1 = *(ulonglong2*)&TBW[wv][y][rdP1];
        ulonglong2 Q0 = *(ulonglong2*)&TBW[wv][y][rdQ0];
        ulonglong2 Q1 = *(ulonglong2*)&TBW[wv][y][rdQ1];
        u64 p[4] = {P0.x, P0.y, P1.x, P1.y};
        u64 q[4] = {Q0.x, Q0.y, Q1.x, Q1.y};
#pragma unroll
        for (int i = 0; i < 4; i++)
#pragma unroll
          for (int j = 0; j < 4; j++)
            acc[i][j] += (int)__popcll(p[i] & q[j]);
      }
    }

    // epilogue: registers + per-wave meta/pred LDS, scalar accumulation
#pragma unroll
    for (int i = 0; i < 4; i++) {
      int pl = 4 * lp + i;
      int pg = mNode[wv][pl];
      if (pg < 0) continue;
      int li  = mLab[wv][pl];
      int dgp = mDeg[wv][pl];
      int sp  = mSelf[wv][pl];
      float pp = mPos[wv][pl];
#pragma unroll
      for (int j = 0; j < 4; j++) {
        int qr = 4 * lq + j;
        int qg = mNode[wv][BH + qr];
        if (qg < 0) continue;
        int lj = mLab[wv][BH + qr];
        if (li == lj) continue;                 // off-diag class bins only
        if (diag && pl >= qr) continue;         // unordered once on diag tiles
        int inter = acc[i][j];
        int apq = (int)((rwp[i][j] >> COLB(qg)) & 1ULL);
        int aqp = (int)((rwq[i][j] >> COLB(pg)) & 1ULL);
        int sq  = mSelf[wv][BH + qr];
        int sub_f = dgp - inter - (apq & (sq ^ 1));
        int sub_r = mDeg[wv][BH + qr] - inter - (aqp & (sp ^ 1));
        float rden = 1.f / (1.f + S1F * (float)inter);
        float xf = (1.f + S1F * (float)sub_f) * rden;
        float xr = (1.f + S1F * (float)sub_r) * rden;
        float Ef = __expf(predT[wv][BH + qr][li] - pp);
        float Er = __expf(predT[wv][pl][lj] - mPos[wv][BH + qr]);
        float vf = 1.f / (1.f + __expf(xf));    // 1 - sigmoid(x)
        float vr = 1.f / (1.f + __expf(xr));
        lsum += Ef * vf * wLDS[li * NC + lj] + Er * vr * wLDS[lj * NC + li];
      }
    }
    // next tile: wave-order DS makes LDS rewrite safe without barriers
  }

  // block reduce: wave shuffle -> 4 partials -> one atomic
  for (int d = 1; d < 64; d <<= 1) lsum += __shfl_xor(lsum, d);
  if (lane == 0) wred[wv] = lsum;
  __syncthreads();
  if (tid == 0) atomicAdd(gLoss, wred[0] + wred[1] + wred[2] + wred[3]);
}

// ---- kernel 4: final assembly ---------------------------------------------
__global__ void fin_kernel(const float* __restrict__ ceAcc,
                           const float* __restrict__ gLoss,
                           float* __restrict__ out) {
  out[0] = ceAcc[0] / (float)NN + gLoss[0];
}

// ---- launch ---------------------------------------------------------------
extern "C" void kernel_launch(void* const* d_in, const int* in_sizes, int n_in,
                              void* d_out, int out_size, void* d_ws, size_t ws_size,
                              hipStream_t stream) {
  const float* preds  = (const float*)d_in[0];
  const int*   labels = (const int*)d_in[1];
  const int*   mask   = (const int*)d_in[2];
  const int*   adj    = (const int*)d_in[3];

  char* ws = (char*)d_ws;
  u64*   bits  = (u64*)(ws + OFF_BITS);
  int*   deg   = (int*)(ws + OFF_DEG);
  float* pos   = (float*)(ws + OFF_POS);
  int*   list  = (int*)(ws + OFF_LIST);
  char*  accb  = ws + OFF_ACC;
  float* ceAcc = (float*)(accb + A_CE);
  float* gLoss = (float*)(accb + A_LOSS);
  int*   Mcnt  = (int*)(accb + A_MCNT);
  int*   Ncnt  = (int*)(accb + A_NCNT);
  int*   gD    = (int*)(accb + A_GD);
  int*   gE    = (int*)(accb + A_GE);
  u64*   gSI   = (u64*)(accb + A_GSI);
  int*   cnt   = (int*)(ws + OFF_CNT);

  hipMemsetAsync(ws + OFF_ACC, 0, 1536 + 163840, stream);

  hipLaunchKernelGGL(pack_bits_kernel, dim3(NN), dim3(256), 0, stream,
                     adj, bits, deg, cnt, labels, mask);
  hipLaunchKernelGGL(mid_kernel, dim3(33), dim3(256), 0, stream,
                     preds, labels, mask, bits, deg, cnt,
                     pos, Ncnt, ceAcc, list, Mcnt, gSI, gE, gD);
  // M=2048 -> 2080 tiles; 520 blocks x 4 waves = 2080 (1 tile/wave)
  hipLaunchKernelGGL(pair_kernel, dim3(520), dim3(256), 0, stream,
                     bits, deg, pos, preds, labels, list, Mcnt, Ncnt,
                     gSI, gE, gD, gLoss);
  hipLaunchKernelGGL(fin_kernel, dim3(1), dim3(1), 0, stream,
                     ceAcc, gLoss, (float*)d_out);
}